// Round 1
// baseline (807.225 us; speedup 1.0000x reference)
//
#include <hip/hip_runtime.h>
#include <math.h>

// FFT convolution: y[b,d,:] = (h[d] (*) x[b,d])[0:L] + x[b,d,:]*B[d]
// L = 8192, pad to M = 16384 for linear conv. Real FFT via packed
// N = 8192 complex FFT. One workgroup per (b,d) row; FFT in 64KB LDS.
// DIF forward (natural->bitrev), untangle/mul/repack in bitrev address
// space (pair-closed per thread), DIT inverse (bitrev->natural).

#define FFT_N  8192
#define LOG_N  13
#define SEQ_L  8192
#define DIM_D  1024
#define NTHR   512
#define BPT    8          // butterflies per thread per stage (N/2/NTHR)

__device__ __forceinline__ float2 cmulf(float2 a, float2 b) {
    return make_float2(a.x * b.x - a.y * b.y, a.x * b.y + a.y * b.x);
}

__device__ __forceinline__ int rev13(int k) {
    return (int)(__brev((unsigned)k) >> (32 - LOG_N));
}

// In-place DIF FFT (e^{-i...}): natural-order input, bit-reversed output.
__device__ void fft_dif(float2* z, int tid) {
    for (int s = 0; s < LOG_N; ++s) {
        const int span = FFT_N >> (s + 1);
        const float ascale = -(float)M_PI / (float)span;
        #pragma unroll
        for (int j = 0; j < BPT; ++j) {
            const int bf  = tid + NTHR * j;
            const int pos = bf & (span - 1);
            const int blk = bf >> (LOG_N - 1 - s);
            const int i0  = (blk << (LOG_N - s)) + pos;
            const int i1  = i0 + span;
            float2 u = z[i0];
            float2 v = z[i1];
            float sn, cs;
            __sincosf(ascale * (float)pos, &sn, &cs);
            float2 d = make_float2(u.x - v.x, u.y - v.y);
            z[i0] = make_float2(u.x + v.x, u.y + v.y);
            z[i1] = make_float2(d.x * cs - d.y * sn, d.x * sn + d.y * cs);
        }
        __syncthreads();
    }
}

// In-place DIT inverse FFT (e^{+i...}), unnormalized:
// bit-reversed input, natural-order output.
__device__ void ifft_dit(float2* z, int tid) {
    for (int s = 0; s < LOG_N; ++s) {
        const int span = 1 << s;
        const float ascale = (float)M_PI / (float)span;
        #pragma unroll
        for (int j = 0; j < BPT; ++j) {
            const int bf  = tid + NTHR * j;
            const int pos = bf & (span - 1);
            const int blk = bf >> s;
            const int i0  = (blk << (s + 1)) + pos;
            const int i1  = i0 + span;
            float2 u = z[i0];
            float2 v = z[i1];
            float sn, cs;
            __sincosf(ascale * (float)pos, &sn, &cs);
            float2 vw = make_float2(v.x * cs - v.y * sn, v.x * sn + v.y * cs);
            z[i0] = make_float2(u.x + vw.x, u.y + vw.y);
            z[i1] = make_float2(u.x - vw.x, u.y - vw.y);
        }
        __syncthreads();
    }
}

__global__ __launch_bounds__(NTHR)
void fftconv_kernel(const float* __restrict__ h,
                    const float* __restrict__ x,
                    const float* __restrict__ Bv,
                    float* __restrict__ y)
{
    __shared__ float2 z[FFT_N];   // exactly 64 KB
    const int tid = (int)threadIdx.x;
    const int d   = (int)blockIdx.x;
    const int b   = (int)blockIdx.y;

    const float Bd = Bv[d];
    const float* hrow = h + (size_t)d * SEQ_L;
    const float* xrow = x + ((size_t)b * DIM_D + (size_t)d) * SEQ_L;
    float*       yrow = y + ((size_t)b * DIM_D + (size_t)d) * SEQ_L;

    const float invN = 1.0f / (float)FFT_N;
    const float tw_scale = -(float)M_PI * invN;   // angle per unit p for e^{-i pi p / N}

    // ---- 1) pack h (zero-padded to 16384) into z, FFT ----
    #pragma unroll
    for (int j = 0; j < BPT; ++j) {
        const int n = tid + NTHR * j;          // 0..4095
        const float2 hv = *(const float2*)(hrow + 2 * n);
        z[n] = hv;
        z[n + FFT_N / 2] = make_float2(0.0f, 0.0f);
    }
    __syncthreads();
    fft_dif(z, tid);

    // ---- 2) untangle h spectrum into registers (pairs p, N-p) ----
    // A[p] = E + t*O ; A[N-p] = conj(E - t*O), t = e^{-i pi p / N}
    float2 Ah[9], Gh[9];
    #pragma unroll
    for (int j = 0; j < 9; ++j) {
        if (j == 8 && tid != 0) continue;      // only thread 0 takes p = N/2
        const int p  = (j < 8) ? (tid + NTHR * j) : (FFT_N / 2);
        const int ap = rev13(p);
        const int am = rev13((FFT_N - p) & (FFT_N - 1));
        const float2 zk  = z[ap];
        const float2 znk = z[am];
        const float2 E = make_float2(0.5f * (zk.x + znk.x), 0.5f * (zk.y - znk.y));
        const float2 O = make_float2(0.5f * (zk.y + znk.y), -0.5f * (zk.x - znk.x));
        float sn, cs;
        __sincosf(tw_scale * (float)p, &sn, &cs);
        const float2 t  = make_float2(cs, sn);
        const float2 tO = cmulf(t, O);
        Ah[j] = make_float2(E.x + tO.x, E.y + tO.y);
        Gh[j] = make_float2(E.x - tO.x, E.y - tO.y);
    }
    __syncthreads();   // everyone done reading h spectrum before reuse of LDS

    // ---- 3) pack x, FFT ----
    #pragma unroll
    for (int j = 0; j < BPT; ++j) {
        const int n = tid + NTHR * j;
        const float2 xv = *(const float2*)(xrow + 2 * n);
        z[n] = xv;
        z[n + FFT_N / 2] = make_float2(0.0f, 0.0f);
    }
    __syncthreads();
    fft_dif(z, tid);

    // ---- 4) untangle x, multiply spectra, repack W for inverse ----
    // Pair (p, N-p) is closed per thread: read then write same addresses,
    // no barrier needed inside this stage.
    #pragma unroll
    for (int j = 0; j < 9; ++j) {
        if (j == 8 && tid != 0) continue;
        const int p  = (j < 8) ? (tid + NTHR * j) : (FFT_N / 2);
        const int ap = rev13(p);
        const int am = rev13((FFT_N - p) & (FFT_N - 1));
        const float2 zk  = z[ap];
        const float2 znk = z[am];
        const float2 E = make_float2(0.5f * (zk.x + znk.x), 0.5f * (zk.y - znk.y));
        const float2 O = make_float2(0.5f * (zk.y + znk.y), -0.5f * (zk.x - znk.x));
        float sn, cs;
        __sincosf(tw_scale * (float)p, &sn, &cs);
        const float2 t  = make_float2(cs, sn);
        const float2 tO = cmulf(t, O);
        const float2 Xp = make_float2(E.x + tO.x, E.y + tO.y);   // X[p]
        const float2 Xm = make_float2(E.x - tO.x, E.y - tO.y);   // conj(X[N-p])

        const float2 Cp = cmulf(Ah[j], Xp);    // C[p]
        const float2 Cm = cmulf(Gh[j], Xm);    // conj(C[N-p]) = C[p+N]

        const float2 S  = make_float2(0.5f * (Cp.x + Cm.x), 0.5f * (Cp.y + Cm.y));
        const float2 Dd = make_float2(0.5f * (Cp.x - Cm.x), 0.5f * (Cp.y - Cm.y));
        // u = i * conj(t) * Dd ;  i*conj(t) = (sn, cs)
        const float2 u = make_float2(sn * Dd.x - cs * Dd.y, sn * Dd.y + cs * Dd.x);

        // W[p] = S + u ; W[N-p] = conj(S - u) ; fold in 1/N for the inverse
        z[ap] = make_float2((S.x + u.x) * invN, (S.y + u.y) * invN);
        z[am] = make_float2((S.x - u.x) * invN, -(S.y - u.y) * invN);
    }
    __syncthreads();

    // ---- 5) inverse FFT ----
    ifft_dit(z, tid);

    // ---- 6) epilogue: y[t] = c[t] + x[t]*B[d] ; c[2n]=Re w[n], c[2n+1]=Im w[n]
    const float* zf = reinterpret_cast<const float*>(z);
    #pragma unroll
    for (int j = 0; j < 16; ++j) {
        const int t = tid + NTHR * j;
        yrow[t] = zf[t] + xrow[t] * Bd;
    }
}

extern "C" void kernel_launch(void* const* d_in, const int* in_sizes, int n_in,
                              void* d_out, int out_size, void* d_ws, size_t ws_size,
                              hipStream_t stream) {
    const float* h  = (const float*)d_in[0];
    const float* x  = (const float*)d_in[1];
    const float* Bv = (const float*)d_in[2];
    float* y = (float*)d_out;

    const int bsz = out_size / (DIM_D * SEQ_L);   // = 4
    dim3 grid(DIM_D, bsz, 1);
    dim3 block(NTHR, 1, 1);
    hipLaunchKernelGGL(fftconv_kernel, grid, block, 0, stream, h, x, Bv, y);
}